// Round 5
// baseline (575.977 us; speedup 1.0000x reference)
//
#include <hip/hip_runtime.h>

// SpikeFP64ScaleBy2K: each row of 64 {0,1}-floats is a fp64 bit pattern,
// big-endian (element 0 = fp64 bit 63 = sign). out = x with exponent
// (e_x + int(k)) mod 2048; passthrough when k == +/-0. Integer bit ops
// reproduce the float reference exactly (absmax 0, verified R1-R4).
//
// R5: one-shot waves, 4 tiles (16 rows) per wave. All 8 loads issued
// before any dependent compute (8 KB read in flight per wave -> 4x the
// memory-level parallelism of R4); the 4 tile computations are fully
// independent so waits resolve at vmcnt(6/4/2/0), not one vmcnt(0).
// Compute per tile: DPP 16-lane OR-reduce + integer field logic (R4).

typedef unsigned int u32x4 __attribute__((ext_vector_type(4)));

#define DPP_OR(v, ctrl) \
    (v | (unsigned)__builtin_amdgcn_update_dpp(0, (int)(v), (ctrl), 0xF, 0xF, true))

#define TILES_PER_WAVE 4

__global__ __launch_bounds__(256) void spike_fp64_scale_kernel(
    const u32x4* __restrict__ x4,
    const u32x4* __restrict__ k4,
    u32x4* __restrict__ o4)
{
    const int lane = (int)(threadIdx.x & 63);
    const int g    = lane >> 4;      // row within tile (0..3)
    const int j    = lane & 15;      // u32x4 within row (0..15)

    const size_t wid  = (size_t)((blockIdx.x * blockDim.x + threadIdx.x) >> 6);
    const size_t base = wid * (TILES_PER_WAVE * 64) + lane;

    // ---- phase 1: issue every load before any dependent use ----
    u32x4 xv[TILES_PER_WAVE], kv[TILES_PER_WAVE];
    #pragma unroll
    for (int t = 0; t < TILES_PER_WAVE; ++t) {
        xv[t] = x4[base + (size_t)t * 64];
        kv[t] = k4[base + (size_t)t * 64];
    }

    // ---- phase 2: independent per-tile compute + store ----
    #pragma unroll
    for (int t = 0; t < TILES_PER_WAVE; ++t) {
        // pack: nibble bit b = element (4j+b); 1.0f = 0x3F800000, bit 23
        const unsigned nx = ((xv[t][0] >> 23) & 1u) | ((xv[t][1] >> 22) & 2u)
                          | ((xv[t][2] >> 21) & 4u) | ((xv[t][3] >> 20) & 8u);
        const unsigned nk = ((kv[t][0] >> 23) & 1u) | ((kv[t][1] >> 22) & 2u)
                          | ((kv[t][2] >> 21) & 4u) | ((kv[t][3] >> 20) & 8u);

        // element-order 32-bit masks (elements 0..31 hold every needed field)
        const unsigned sh4 = (unsigned)(j & 7) * 4u;
        unsigned uxl = (j < 8) ? (nx << sh4) : 0u;
        unsigned ukl = (j < 8) ? (nk << sh4) : 0u;

        // kzero: any of k's elements 1..63 set? (j==0 excludes the sign)
        const unsigned nkm = nk & ((j == 0) ? 0xEu : 0xFu);
        const unsigned long long bal = __ballot(nkm != 0u);
        const bool kany = ((unsigned)((bal >> (g * 16)) & 0xFFFFull)) != 0u;

        // 16-lane OR-reduce on the VALU pipe (DPP)
        uxl = DPP_OR(uxl, 0xB1);  ukl = DPP_OR(ukl, 0xB1);   // xor 1
        uxl = DPP_OR(uxl, 0x4E);  ukl = DPP_OR(ukl, 0x4E);   // xor 2
        uxl = DPP_OR(uxl, 0x141); ukl = DPP_OR(ukl, 0x141);  // xor 7
        uxl = DPP_OR(uxl, 0x140); ukl = DPP_OR(ukl, 0x140);  // xor 15

        // fields (element e at bit e; bitreverse -> element e at bit 31-e)
        const unsigned bk    = __builtin_bitreverse32(ukl);
        const unsigned ek    = (bk >> 20) & 0x7FFu;
        const unsigned val16 = 0x8000u | ((bk >> 5) & 0x7FFFu);
        const unsigned shv   = (ek + 1u) & 15u;
        const unsigned kabs  = (val16 >> (15u - shv)) & 0x7FFu;
        const unsigned kfin  = (ukl & 1u) ? ((0u - kabs) & 0x7FFu) : kabs;
        const unsigned ex    = (__builtin_bitreverse32(uxl) >> 20) & 0x7FFu;
        const unsigned enew  = (ex + kfin) & 0x7FFu;

        // all-integer epilogue: only elements 1..11 change
        u32x4 o;
        const int e0 = 4 * j;
        #pragma unroll
        for (int c = 0; c < 4; ++c) {
            const int e = e0 + c;
            const unsigned bit  = (enew >> (((unsigned)(11 - e)) & 31u)) & 1u;
            const bool     repl = kany && (e >= 1) && (e <= 11);
            o[c] = repl ? (bit ? 0x3F800000u : 0u) : xv[t][c];
        }
        o4[base + (size_t)t * 64] = o;
    }
}

extern "C" void kernel_launch(void* const* d_in, const int* in_sizes, int n_in,
                              void* d_out, int out_size, void* d_ws, size_t ws_size,
                              hipStream_t stream) {
    const u32x4* x4 = (const u32x4*)d_in[0];
    const u32x4* k4 = (const u32x4*)d_in[1];
    u32x4* o4 = (u32x4*)d_out;

    const int nrows = in_sizes[0] / 64;              // 1048576
    const int ntiles = nrows / 4;                    // 262144
    const int nwaves = ntiles / TILES_PER_WAVE;      // 65536 (exact)
    const int threads = 256;
    const int blocks = (nwaves * 64) / threads;      // 16384, exact

    spike_fp64_scale_kernel<<<blocks, threads, 0, stream>>>(x4, k4, o4);
}

// Round 6
// 553.086 us; speedup vs baseline: 1.0414x; 1.0414x over previous
//
#include <hip/hip_runtime.h>

// SpikeFP64ScaleBy2K: each row of 64 {0,1}-floats is a fp64 bit pattern,
// big-endian (element 0 = fp64 bit 63 = sign). out = x with exponent
// (e_x + int(k)) mod 2048; passthrough when k == +/-0. Integer bit ops
// reproduce the float reference exactly (absmax 0, verified R1-R5).
//
// R6: identical to R4 (best: 176 us) except input loads are non-temporal.
// Inputs are read exactly once; the nt bit stops L2/L3 from retaining the
// 512 MiB dead input stream, freeing the caches to absorb the write stream
// (output lines are resident-dirty from the harness poison).

typedef unsigned int u32x4 __attribute__((ext_vector_type(4)));

#define DPP_OR(v, ctrl) \
    (v | (unsigned)__builtin_amdgcn_update_dpp(0, (int)(v), (ctrl), 0xF, 0xF, true))

__global__ __launch_bounds__(256) void spike_fp64_scale_kernel(
    const u32x4* __restrict__ x4,
    const u32x4* __restrict__ k4,
    u32x4* __restrict__ o4)
{
    const int lane = (int)(threadIdx.x & 63);
    const int g    = lane >> 4;      // row within wave (0..3)
    const int j    = lane & 15;      // u32x4 within row (0..15)

    const size_t idx = (size_t)((blockIdx.x * blockDim.x + threadIdx.x) >> 6) * 64 + lane;
    const u32x4 xv = __builtin_nontemporal_load(&x4[idx]);
    const u32x4 kv = __builtin_nontemporal_load(&k4[idx]);

    // ---- pack: nibble bit b = element (4j+b); 1.0f = 0x3F800000, bit 23 ----
    const unsigned nx = ((xv[0] >> 23) & 1u) | ((xv[1] >> 22) & 2u)
                      | ((xv[2] >> 21) & 4u) | ((xv[3] >> 20) & 8u);
    const unsigned nk = ((kv[0] >> 23) & 1u) | ((kv[1] >> 22) & 2u)
                      | ((kv[2] >> 21) & 4u) | ((kv[3] >> 20) & 8u);

    // element-order 32-bit masks (elements 0..31 hold every needed field)
    const unsigned sh4 = (unsigned)(j & 7) * 4u;
    unsigned uxl = (j < 8) ? (nx << sh4) : 0u;
    unsigned ukl = (j < 8) ? (nk << sh4) : 0u;

    // kzero: any of k's elements 1..63 set? (j==0 excludes element 0 = sign)
    const unsigned nkm = nk & ((j == 0) ? 0xEu : 0xFu);
    const unsigned long long bal = __ballot(nkm != 0u);
    const bool kany = ((unsigned)((bal >> (g * 16)) & 0xFFFFull)) != 0u;

    // ---- 16-lane OR-reduce on the VALU pipe (DPP) ----
    uxl = DPP_OR(uxl, 0xB1);  ukl = DPP_OR(ukl, 0xB1);   // xor 1
    uxl = DPP_OR(uxl, 0x4E);  ukl = DPP_OR(ukl, 0x4E);   // xor 2
    uxl = DPP_OR(uxl, 0x141); ukl = DPP_OR(ukl, 0x141);  // xor 7 (half mirror)
    uxl = DPP_OR(uxl, 0x140); ukl = DPP_OR(ukl, 0x140);  // xor 15 (mirror)

    // ---- fields (element e at bit e; bitreverse -> element e at bit 31-e) ----
    const unsigned bk    = __builtin_bitreverse32(ukl);
    const unsigned ek    = (bk >> 20) & 0x7FFu;             // e_k, MSB-first
    const unsigned val16 = 0x8000u | ((bk >> 5) & 0x7FFFu); // [1, m_k top 15]
    const unsigned shv   = (ek + 1u) & 15u;                 // (e_k-1023) mod 16
    const unsigned kabs  = (val16 >> (15u - shv)) & 0x7FFu; // |k| as integer
    const unsigned kfin  = (ukl & 1u) ? ((0u - kabs) & 0x7FFu) : kabs;
    const unsigned ex    = (__builtin_bitreverse32(uxl) >> 20) & 0x7FFu;
    const unsigned enew  = (ex + kfin) & 0x7FFu;

    // ---- all-integer epilogue: only elements 1..11 change ----
    u32x4 o;
    const int e0 = 4 * j;
    #pragma unroll
    for (int c = 0; c < 4; ++c) {
        const int e = e0 + c;
        const unsigned bit  = (enew >> (((unsigned)(11 - e)) & 31u)) & 1u;
        const bool     repl = kany && (e >= 1) && (e <= 11);
        o[c] = repl ? (bit ? 0x3F800000u : 0u) : xv[c];
    }
    o4[idx] = o;
}

extern "C" void kernel_launch(void* const* d_in, const int* in_sizes, int n_in,
                              void* d_out, int out_size, void* d_ws, size_t ws_size,
                              hipStream_t stream) {
    const u32x4* x4 = (const u32x4*)d_in[0];
    const u32x4* k4 = (const u32x4*)d_in[1];
    u32x4* o4 = (u32x4*)d_out;

    const int nrows = in_sizes[0] / 64;      // 1048576
    const int total_threads = nrows * 16;    // 16 lanes per row
    const int threads = 256;
    const int blocks = total_threads / threads;  // 65536, exact (full waves)

    spike_fp64_scale_kernel<<<blocks, threads, 0, stream>>>(x4, k4, o4);
}

// Round 7
// 548.419 us; speedup vs baseline: 1.0502x; 1.0085x over previous
//
#include <hip/hip_runtime.h>

// SpikeFP64ScaleBy2K: each row of 64 {0,1}-floats is a fp64 bit pattern,
// big-endian (element 0 = fp64 bit 63 = sign). out = x with exponent
// (e_x + int(k)) mod 2048; passthrough when k == +/-0. Integer bit ops
// reproduce the float reference exactly (absmax 0, verified R1-R6).
//
// R7: R6 (NT loads -- the first clear win: kernel fell below the harness
// fill's 162 us) + NT store. Both streams are touch-once; nt keeps them
// out of L2/L3 retention so the caches serve the restore-warmed inputs.

typedef unsigned int u32x4 __attribute__((ext_vector_type(4)));

#define DPP_OR(v, ctrl) \
    (v | (unsigned)__builtin_amdgcn_update_dpp(0, (int)(v), (ctrl), 0xF, 0xF, true))

__global__ __launch_bounds__(256) void spike_fp64_scale_kernel(
    const u32x4* __restrict__ x4,
    const u32x4* __restrict__ k4,
    u32x4* __restrict__ o4)
{
    const int lane = (int)(threadIdx.x & 63);
    const int g    = lane >> 4;      // row within wave (0..3)
    const int j    = lane & 15;      // u32x4 within row (0..15)

    const size_t idx = (size_t)((blockIdx.x * blockDim.x + threadIdx.x) >> 6) * 64 + lane;
    const u32x4 xv = __builtin_nontemporal_load(&x4[idx]);
    const u32x4 kv = __builtin_nontemporal_load(&k4[idx]);

    // ---- pack: nibble bit b = element (4j+b); 1.0f = 0x3F800000, bit 23 ----
    const unsigned nx = ((xv[0] >> 23) & 1u) | ((xv[1] >> 22) & 2u)
                      | ((xv[2] >> 21) & 4u) | ((xv[3] >> 20) & 8u);
    const unsigned nk = ((kv[0] >> 23) & 1u) | ((kv[1] >> 22) & 2u)
                      | ((kv[2] >> 21) & 4u) | ((kv[3] >> 20) & 8u);

    // element-order 32-bit masks (elements 0..31 hold every needed field)
    const unsigned sh4 = (unsigned)(j & 7) * 4u;
    unsigned uxl = (j < 8) ? (nx << sh4) : 0u;
    unsigned ukl = (j < 8) ? (nk << sh4) : 0u;

    // kzero: any of k's elements 1..63 set? (j==0 excludes element 0 = sign)
    const unsigned nkm = nk & ((j == 0) ? 0xEu : 0xFu);
    const unsigned long long bal = __ballot(nkm != 0u);
    const bool kany = ((unsigned)((bal >> (g * 16)) & 0xFFFFull)) != 0u;

    // ---- 16-lane OR-reduce on the VALU pipe (DPP) ----
    uxl = DPP_OR(uxl, 0xB1);  ukl = DPP_OR(ukl, 0xB1);   // xor 1
    uxl = DPP_OR(uxl, 0x4E);  ukl = DPP_OR(ukl, 0x4E);   // xor 2
    uxl = DPP_OR(uxl, 0x141); ukl = DPP_OR(ukl, 0x141);  // xor 7 (half mirror)
    uxl = DPP_OR(uxl, 0x140); ukl = DPP_OR(ukl, 0x140);  // xor 15 (mirror)

    // ---- fields (element e at bit e; bitreverse -> element e at bit 31-e) ----
    const unsigned bk    = __builtin_bitreverse32(ukl);
    const unsigned ek    = (bk >> 20) & 0x7FFu;             // e_k, MSB-first
    const unsigned val16 = 0x8000u | ((bk >> 5) & 0x7FFFu); // [1, m_k top 15]
    const unsigned shv   = (ek + 1u) & 15u;                 // (e_k-1023) mod 16
    const unsigned kabs  = (val16 >> (15u - shv)) & 0x7FFu; // |k| as integer
    const unsigned kfin  = (ukl & 1u) ? ((0u - kabs) & 0x7FFu) : kabs;
    const unsigned ex    = (__builtin_bitreverse32(uxl) >> 20) & 0x7FFu;
    const unsigned enew  = (ex + kfin) & 0x7FFu;

    // ---- all-integer epilogue: only elements 1..11 change ----
    u32x4 o;
    const int e0 = 4 * j;
    #pragma unroll
    for (int c = 0; c < 4; ++c) {
        const int e = e0 + c;
        const unsigned bit  = (enew >> (((unsigned)(11 - e)) & 31u)) & 1u;
        const bool     repl = kany && (e >= 1) && (e <= 11);
        o[c] = repl ? (bit ? 0x3F800000u : 0u) : xv[c];
    }
    __builtin_nontemporal_store(o, &o4[idx]);
}

extern "C" void kernel_launch(void* const* d_in, const int* in_sizes, int n_in,
                              void* d_out, int out_size, void* d_ws, size_t ws_size,
                              hipStream_t stream) {
    const u32x4* x4 = (const u32x4*)d_in[0];
    const u32x4* k4 = (const u32x4*)d_in[1];
    u32x4* o4 = (u32x4*)d_out;

    const int nrows = in_sizes[0] / 64;      // 1048576
    const int total_threads = nrows * 16;    // 16 lanes per row
    const int threads = 256;
    const int blocks = total_threads / threads;  // 65536, exact (full waves)

    spike_fp64_scale_kernel<<<blocks, threads, 0, stream>>>(x4, k4, o4);
}